// Round 1
// baseline (504.400 us; speedup 1.0000x reference)
//
#include <hip/hip_runtime.h>
#include <hip/hip_bf16.h>

// Problem constants (validated against in_sizes at launch where cheap)
#define LN_F 128
#define S_DIM 16

typedef __attribute__((ext_vector_type(8))) __bf16 bf16x8;
typedef __attribute__((ext_vector_type(4))) float f32x4;

__device__ __forceinline__ unsigned short f2bf(float f) {
    unsigned u = __float_as_uint(f);
    u = u + 0x7FFFu + ((u >> 16) & 1u);   // round-to-nearest-even
    return (unsigned short)(u >> 16);
}
__device__ __forceinline__ float fast_tanh(float x) {
    x = fminf(10.f, fmaxf(-10.f, x));
    float e = __expf(2.f * x);
    return __fdividef(e - 1.f, e + 1.f);
}

// ---------------- conversion kernels ----------------
// emb f32[V,128] -> bf16[V,128]
__global__ void k_conv_emb(const float* __restrict__ src,
                           unsigned short* __restrict__ dst, int n8) {
    int i = blockIdx.x * blockDim.x + threadIdx.x;
    if (i >= n8) return;
    const float4* s = (const float4*)src;
    float4 a = s[i * 2], b = s[i * 2 + 1];
    uint4 o;
    o.x = (unsigned)f2bf(a.x) | ((unsigned)f2bf(a.y) << 16);
    o.y = (unsigned)f2bf(a.z) | ((unsigned)f2bf(a.w) << 16);
    o.z = (unsigned)f2bf(b.x) | ((unsigned)f2bf(b.y) << 16);
    o.w = (unsigned)f2bf(b.z) | ((unsigned)f2bf(b.w) << 16);
    ((uint4*)dst)[i] = o;
}

// xi_w f32[256(k),256(c)] -> bf16 transposed [c][k], XOR-swizzled 16B granules
__global__ void k_conv_xi(const float* __restrict__ w, unsigned short* __restrict__ dst) {
    int t = blockIdx.x * blockDim.x + threadIdx.x;
    if (t >= 256 * 32) return;
    int c = t >> 5, g = t & 31;
    unsigned short u[8];
#pragma unroll
    for (int j = 0; j < 8; ++j) u[j] = f2bf(w[(g * 8 + j) * 256 + c]);
    uint4 o;
    o.x = (unsigned)u[0] | ((unsigned)u[1] << 16);
    o.y = (unsigned)u[2] | ((unsigned)u[3] << 16);
    o.z = (unsigned)u[4] | ((unsigned)u[5] << 16);
    o.w = (unsigned)u[6] | ((unsigned)u[7] << 16);
    ((uint4*)dst)[c * 32 + (g ^ (c & 7))] = o;
}

// rou_w f32[128(k),16(c)] -> bf16 transposed [c][k], swizzled
__global__ void k_conv_rou(const float* __restrict__ w, unsigned short* __restrict__ dst) {
    int t = blockIdx.x * blockDim.x + threadIdx.x;
    if (t >= 16 * 16) return;
    int c = t >> 4, g = t & 15;
    unsigned short u[8];
#pragma unroll
    for (int j = 0; j < 8; ++j) u[j] = f2bf(w[(g * 8 + j) * 16 + c]);
    uint4 o;
    o.x = (unsigned)u[0] | ((unsigned)u[1] << 16);
    o.y = (unsigned)u[2] | ((unsigned)u[3] << 16);
    o.z = (unsigned)u[4] | ((unsigned)u[5] << 16);
    o.w = (unsigned)u[6] | ((unsigned)u[7] << 16);
    ((uint4*)dst)[c * 16 + (g ^ (c & 7))] = o;
}

// ---------------- A = tanh(X @ xi_w + xi_b) * (mu/s/dg), bf16 out ----------------
// grid.x = ceil(n/256), grid.y = 2 (column halves), block = 512 (8 waves, 32 edges/wave)
__global__ __launch_bounds__(512) void k_A(
    const int* __restrict__ Xn, const int* __restrict__ Xe, const int* __restrict__ dg,
    const unsigned short* __restrict__ embb, const uint4* __restrict__ xiT,
    const float* __restrict__ xib, unsigned short* __restrict__ Aout,
    int ebase, int n) {
    __shared__ uint4 sB[4096];   // 64KB: half of xi_w^T (128 cols x 256 k), bf16 swizzled
    const int half = blockIdx.y;
    for (int i = threadIdx.x; i < 4096; i += 512) sB[i] = xiT[half * 4096 + i];
    __syncthreads();

    const int wave = threadIdx.x >> 6, lane = threadIdx.x & 63;
    const int j = lane & 15, kg = lane >> 4;
    const int wbase = blockIdx.x * 256 + wave * 32;   // local edge base of this wave

    int le0 = wbase + j, le1 = le0 + 16;
    int ce0 = min(le0, n - 1), ce1 = min(le1, n - 1);
    int s0 = Xn[ebase + ce0], s1 = Xn[ebase + ce1];
    int t0 = Xe[ebase + ce0], t1 = Xe[ebase + ce1];

    f32x4 acc[2][8] = {};
#pragma unroll
    for (int kc = 0; kc < 8; ++kc) {
        int n0 = (kc < 4) ? s0 : t0;
        int n1 = (kc < 4) ? s1 : t1;
        int off = (kc & 3) * 32 + kg * 8;
        bf16x8 a0 = *(const bf16x8*)(embb + (size_t)n0 * 128 + off);
        bf16x8 a1 = *(const bf16x8*)(embb + (size_t)n1 * 128 + off);
        int g = kc * 4 + kg;
#pragma unroll
        for (int ct = 0; ct < 8; ++ct) {
            int col_l = ct * 16 + j;
            bf16x8 bfr = ((const bf16x8*)sB)[col_l * 32 + (g ^ (j & 7))];
            acc[0][ct] = __builtin_amdgcn_mfma_f32_16x16x32_bf16(a0, bfr, acc[0][ct], 0, 0, 0);
            acc[1][ct] = __builtin_amdgcn_mfma_f32_16x16x32_bf16(a1, bfr, acc[1][ct], 0, 0, 0);
        }
    }
    // epilogue: C/D layout: col = ct*16 + (lane&15), row = (lane>>4)*4 + reg
#pragma unroll
    for (int gi = 0; gi < 2; ++gi) {
#pragma unroll
        for (int r = 0; r < 4; ++r) {
            int le = wbase + gi * 16 + kg * 4 + r;
            if (le < n) {
                int ge = ebase + le;
                float scale = __fdividef(0.9f / 16.f, (float)dg[ge]);
#pragma unroll
                for (int ct = 0; ct < 8; ++ct) {
                    int col = half * 128 + ct * 16 + j;
                    float v = fast_tanh(acc[gi][ct][r] + xib[col]) * scale;
                    Aout[(size_t)le * 256 + col] = f2bf(v);
                }
            }
        }
    }
}

// ---------------- b = tanh(emb[src] @ rou_w + rou_b), f32 out ----------------
__global__ __launch_bounds__(512) void k_b(
    const int* __restrict__ Xn, const unsigned short* __restrict__ embb,
    const uint4* __restrict__ rouT, const float* __restrict__ roub,
    float* __restrict__ bout, int n) {
    __shared__ uint4 sR[256];   // 4KB
    if (threadIdx.x < 256) sR[threadIdx.x] = rouT[threadIdx.x];
    __syncthreads();

    const int wave = threadIdx.x >> 6, lane = threadIdx.x & 63;
    const int j = lane & 15, kg = lane >> 4;
    const int wbase = blockIdx.x * 256 + wave * 32;

    int le0 = wbase + j, le1 = le0 + 16;
    int ce0 = min(le0, n - 1), ce1 = min(le1, n - 1);
    int s0 = Xn[ce0], s1 = Xn[ce1];

    f32x4 acc0 = {}, acc1 = {};
#pragma unroll
    for (int kc = 0; kc < 4; ++kc) {
        int off = kc * 32 + kg * 8;
        bf16x8 a0 = *(const bf16x8*)(embb + (size_t)s0 * 128 + off);
        bf16x8 a1 = *(const bf16x8*)(embb + (size_t)s1 * 128 + off);
        int g = kc * 4 + kg;
        bf16x8 bfr = ((const bf16x8*)sR)[j * 16 + (g ^ (j & 7))];
        acc0 = __builtin_amdgcn_mfma_f32_16x16x32_bf16(a0, bfr, acc0, 0, 0, 0);
        acc1 = __builtin_amdgcn_mfma_f32_16x16x32_bf16(a1, bfr, acc1, 0, 0, 0);
    }
    float rbj = roub[j];
#pragma unroll
    for (int gi = 0; gi < 2; ++gi) {
        const f32x4& a = gi ? acc1 : acc0;
#pragma unroll
        for (int r = 0; r < 4; ++r) {
            int le = wbase + gi * 16 + kg * 4 + r;
            if (le < n) bout[(size_t)le * 16 + j] = fast_tanh(a[r] + rbj);
        }
    }
}

// ---------------- scatter: states += per-edge b ----------------
__global__ void k_scatter_b(const float* __restrict__ b, const int* __restrict__ Xe,
                            float* __restrict__ st, int n) {
    int t = blockIdx.x * blockDim.x + threadIdx.x;
    if (t >= n * 16) return;
    int e = t >> 4, s = t & 15;
    atomicAdd(st + (size_t)Xe[e] * 16 + s, b[t]);
}

// ---------------- propagation: states_new = scatter( A @ states_prev[src] + b ) ----------------
// 16 threads per edge, lane s handles one output element
__global__ void k_prop(const unsigned short* __restrict__ A, const float* __restrict__ b,
                       const int* __restrict__ Xn, const int* __restrict__ Xe,
                       const float* __restrict__ sp, float* __restrict__ sn,
                       int ebase, int n) {
    int t = blockIdx.x * blockDim.x + threadIdx.x;
    int le = t >> 4;
    if (le >= n) return;
    int s = t & 15;
    int ge = ebase + le;
    int node = Xn[ge], nbr = Xe[ge];
    const float4* hp = (const float4*)(sp + (size_t)node * 16);
    float4 h0 = hp[0], h1 = hp[1], h2 = hp[2], h3 = hp[3];
    float hv[16] = {h0.x, h0.y, h0.z, h0.w, h1.x, h1.y, h1.z, h1.w,
                    h2.x, h2.y, h2.z, h2.w, h3.x, h3.y, h3.z, h3.w};
    const uint4* ar = (const uint4*)(A + (size_t)le * 256 + s * 16);
    uint4 q0 = ar[0], q1 = ar[1];
    unsigned uu[8] = {q0.x, q0.y, q0.z, q0.w, q1.x, q1.y, q1.z, q1.w};
    float acc = b[(size_t)ge * 16 + s];
#pragma unroll
    for (int m = 0; m < 8; ++m) {
        acc += __uint_as_float(uu[m] << 16) * hv[2 * m];
        acc += __uint_as_float(uu[m] & 0xffff0000u) * hv[2 * m + 1];
    }
    atomicAdd(sn + (size_t)nbr * 16 + s, acc);
}

// ---------------- final: softmax( [emb, states] @ lin_w + lin_b ) ----------------
__global__ void k_final(const float* __restrict__ emb, const float* __restrict__ st,
                        const float* __restrict__ lw, const float* __restrict__ lb,
                        float* __restrict__ out, int nv) {
    __shared__ float sw[435];
    for (int i = threadIdx.x; i < 435; i += 256) sw[i] = (i < 432) ? lw[i] : lb[i - 432];
    __syncthreads();
    int t = blockIdx.x * blockDim.x + threadIdx.x;
    int v = t >> 4, j = t & 15;
    if (v >= nv) return;
    float a0 = 0.f, a1 = 0.f, a2 = 0.f;
#pragma unroll
    for (int m = 0; m < 8; ++m) {
        int i = m * 16 + j;
        float x = emb[(size_t)v * 128 + i];
        a0 += x * sw[i * 3]; a1 += x * sw[i * 3 + 1]; a2 += x * sw[i * 3 + 2];
    }
    float xs = st[(size_t)v * 16 + j];
    a0 += xs * sw[(128 + j) * 3]; a1 += xs * sw[(128 + j) * 3 + 1]; a2 += xs * sw[(128 + j) * 3 + 2];
#pragma unroll
    for (int m = 1; m < 16; m <<= 1) {
        a0 += __shfl_xor(a0, m, 64);
        a1 += __shfl_xor(a1, m, 64);
        a2 += __shfl_xor(a2, m, 64);
    }
    if (j == 0) {
        a0 += sw[432]; a1 += sw[433]; a2 += sw[434];
        float mx = fmaxf(a0, fmaxf(a1, a2));
        float e0 = __expf(a0 - mx), e1 = __expf(a1 - mx), e2 = __expf(a2 - mx);
        float inv = 1.f / (e0 + e1 + e2);
        out[(size_t)v * 3 + 0] = e0 * inv;
        out[(size_t)v * 3 + 1] = e1 * inv;
        out[(size_t)v * 3 + 2] = e2 * inv;
    }
}

extern "C" void kernel_launch(void* const* d_in, const int* in_sizes, int n_in,
                              void* d_out, int out_size, void* d_ws, size_t ws_size,
                              hipStream_t stream) {
    const int*   Xn  = (const int*)d_in[0];
    const int*   Xe  = (const int*)d_in[1];
    const int*   dg  = (const int*)d_in[2];
    const float* emb = (const float*)d_in[3];
    const float* xiw = (const float*)d_in[4];
    const float* xib = (const float*)d_in[5];
    const float* rw  = (const float*)d_in[6];
    const float* rb  = (const float*)d_in[7];
    const float* lw  = (const float*)d_in[8];
    const float* lb  = (const float*)d_in[9];
    float* out = (float*)d_out;
    const int E = in_sizes[0];
    const int V = in_sizes[3] / LN_F;

    // workspace carve (256B aligned)
    char* p = (char*)d_ws;
    auto carve = [&](size_t bytes) {
        char* q = p; p += (bytes + 255) & ~(size_t)255; return q;
    };
    unsigned short* embb = (unsigned short*)carve((size_t)V * 128 * 2);
    uint4* xiT  = (uint4*)carve(131072);
    uint4* rouT = (uint4*)carve(4096);
    float* bbuf = (float*)carve((size_t)E * 16 * 4);
    float* stA  = (float*)carve((size_t)V * 16 * 4);
    float* stB  = (float*)carve((size_t)V * 16 * 4);
    unsigned short* Abuf = (unsigned short*)p;
    size_t used = (size_t)(p - (char*)d_ws);
    size_t remain = (ws_size > used) ? (ws_size - used) : 0;
    size_t needA = (size_t)E * 256 * 2;
    bool full = remain >= needA;
    int chunk;
    if (full) chunk = E;
    else {
        size_t c = (remain / 512) & ~(size_t)255;
        if (c < 256) c = 256;            // last-resort (assumes ws is at least ~52MB+128KB)
        chunk = (int)((c < (size_t)E) ? c : (size_t)E);
    }

    k_conv_emb<<<(V * 128 / 8 + 255) / 256, 256, 0, stream>>>(emb, embb, V * 128 / 8);
    k_conv_xi<<<32, 256, 0, stream>>>(xiw, (unsigned short*)xiT);
    k_conv_rou<<<1, 256, 0, stream>>>(rw, (unsigned short*)rouT);

    // b for all edges
    k_b<<<(E + 255) / 256, 512, 0, stream>>>(Xn, embb, rouT, rb, bbuf, E);

    // step 1: states1 = segment_sum(b)  (states0 == 0)
    hipMemsetAsync(stA, 0, (size_t)V * 16 * 4, stream);
    k_scatter_b<<<((size_t)E * 16 + 255) / 256, 256, 0, stream>>>(bbuf, Xe, stA, E);

    if (full) {
        dim3 g((E + 255) / 256, 2);
        k_A<<<g, 512, 0, stream>>>(Xn, Xe, dg, embb, xiT, xib, Abuf, 0, E);
    }

    float* sp = stA;
    float* sn = stB;
    for (int step = 1; step < 3; ++step) {
        hipMemsetAsync(sn, 0, (size_t)V * 16 * 4, stream);
        for (int base = 0; base < E; base += chunk) {
            int nn = (E - base < chunk) ? (E - base) : chunk;
            if (!full) {
                dim3 g((nn + 255) / 256, 2);
                k_A<<<g, 512, 0, stream>>>(Xn, Xe, dg, embb, xiT, xib, Abuf, base, nn);
            }
            const unsigned short* Ap = full ? (Abuf + (size_t)base * 256) : Abuf;
            k_prop<<<((size_t)nn * 16 + 255) / 256, 256, 0, stream>>>(
                Ap, bbuf, Xn, Xe, sp, sn, base, nn);
        }
        float* tmp = sp; sp = sn; sn = tmp;
    }

    k_final<<<((size_t)V * 16 + 255) / 256, 256, 0, stream>>>(emb, sp, lw, lb, out, V);
}